// Round 1
// baseline (415.097 us; speedup 1.0000x reference)
//
#include <hip/hip_runtime.h>

// GCNN via FFT over the cyclic group C_256.
//
// DenseSymm:  x0[b,f,g] = sum_i x[b,i] w_symm[(i+g)%N, f] + b_symm[f]
//             -> Fourier: H0[b,f,k] = conj(Xhat[b,k]) * WsHat[k,f]  (+ 256*b_symm at k=0)
// Eq layer l: y[b,fo,go] = sum_{gi,fi} x[b,fi,gi] w_eq[l,(go-gi)%G,fi,fo] + b_eq
//             -> Fourier: Yhat[b,fo,k] = sum_fi Hhat[b,fi,k] * WeqHat[l,k,fi,fo]
//             (WeqHat pre-scaled by 1/256 so the inverse FFT is unnormalized;
//              bias is added at bin k=0 which adds it to every g)
// Real signals -> Hermitian spectra: only bins 0..128 are stored/processed.
// One block = 4 batch rows; all intermediate state stays in LDS.

#define NG 256
#define NF 32
#define KB 129
#define NLAYER 3
#define HS_STRIDE 4132  // 32*129 + 4 pad (float2 units) per nb-slab, breaks 4-way bank aliasing

// -------- one-wave in-LDS radix-2 FFT of 256 complex points --------
__device__ __forceinline__ void wave_fft256(float2* __restrict__ s,
                                            const float2* __restrict__ tw,
                                            int lane, bool inv) {
  asm volatile("s_waitcnt lgkmcnt(0)" ::: "memory");
  // bit-reversal permutation (8-bit)
  #pragma unroll
  for (int t = 0; t < 4; ++t) {
    int i = t * 64 + lane;
    int j = (int)(__brev((unsigned)i) >> 24);
    if (j > i) { float2 a = s[i]; float2 b = s[j]; s[i] = b; s[j] = a; }
  }
  asm volatile("s_waitcnt lgkmcnt(0)" ::: "memory");
  #pragma unroll
  for (int st = 0; st < 8; ++st) {
    const int half = 1 << st;
    const int tshift = 7 - st;  // twiddle index = off * (256/len), len = 2<<st
    #pragma unroll
    for (int t = 0; t < 2; ++t) {
      int bf = t * 64 + lane;              // butterfly id 0..127
      int off = bf & (half - 1);
      int blk = bf >> st;
      int i = (blk << (st + 1)) + off;
      int j = i + half;
      float2 wv = tw[off << tshift];
      float wy = inv ? -wv.y : wv.y;
      float2 u = s[i];
      float2 v = s[j];
      float vr = v.x * wv.x - v.y * wy;
      float vi = v.x * wy + v.y * wv.x;
      s[i] = make_float2(u.x + vr, u.y + vi);
      s[j] = make_float2(u.x - vr, u.y - vi);
    }
    asm volatile("s_waitcnt lgkmcnt(0)" ::: "memory");
  }
}

// -------- weight FFT prep: WsHat[f][k], WeqHat[((l*32+fi)*129+k)*32+fo] --------
__global__ __launch_bounds__(256) void gcnn_wfft(
    const float* __restrict__ w_symm, const float* __restrict__ w_eq,
    float2* __restrict__ Ws_hat, float2* __restrict__ Weq_hat) {
  __shared__ float2 fbw[4][256];
  __shared__ float2 twl[256];
  const int tid = threadIdx.x;
  const int w = tid >> 6;
  const int lane = tid & 63;
  {
    float a = (float)tid * 0.0245436926f;  // 2*pi/256
    twl[tid] = make_float2(cosf(a), -sinf(a));
  }
  __syncthreads();
  const int task = blockIdx.x * 4 + w;  // grid 776 * 4 = 3104 tasks exactly
  if (task < 32) {
    const int f = task;
    for (int g = lane; g < 256; g += 64)
      fbw[w][g] = make_float2(w_symm[g * 32 + f], 0.f);
    wave_fft256(&fbw[w][0], twl, lane, false);
    for (int k = lane; k < KB; k += 64) Ws_hat[f * KB + k] = fbw[w][k];
  } else {
    const int idx = task - 32;
    const int l = idx >> 10;
    const int fi = (idx >> 5) & 31;
    const int fo = idx & 31;
    for (int g = lane; g < 256; g += 64)
      fbw[w][g] = make_float2(w_eq[((size_t)(l * 256 + g) * 32 + fi) * 32 + fo] * (1.f / 256.f), 0.f);
    wave_fft256(&fbw[w][0], twl, lane, false);
    for (int k = lane; k < KB; k += 64)
      Weq_hat[((size_t)((l * 32 + fi) * KB + k)) * 32 + fo] = fbw[w][k];
  }
}

// -------- per-lane spectral GEMM on one (nb, k) column, in place --------
__device__ __forceinline__ void gemm_col(float2* __restrict__ Hs,
                                         const float2* __restrict__ Weq_hat,
                                         const float* __restrict__ b_eq,
                                         int l, int nb, int k) {
  float2 acc[32];
  #pragma unroll
  for (int fo = 0; fo < 32; ++fo) acc[fo] = make_float2(0.f, 0.f);
  const float2* hcol = Hs + nb * HS_STRIDE + k;
  #pragma unroll 2
  for (int fi = 0; fi < 32; ++fi) {
    float2 h = hcol[fi * KB];
    const float4* wp = reinterpret_cast<const float4*>(
        Weq_hat + ((size_t)((l * 32 + fi) * KB + k)) * 32);
    #pragma unroll
    for (int q = 0; q < 16; ++q) {
      float4 v = wp[q];
      acc[2 * q].x     += h.x * v.x - h.y * v.y;
      acc[2 * q].y     += h.x * v.y + h.y * v.x;
      acc[2 * q + 1].x += h.x * v.z - h.y * v.w;
      acc[2 * q + 1].y += h.x * v.w + h.y * v.z;
    }
  }
  if (k == 0) {
    #pragma unroll
    for (int fo = 0; fo < 32; ++fo) acc[fo].x += b_eq[l * 32 + fo];
  }
  float2* hw = Hs + nb * HS_STRIDE + k;
  #pragma unroll
  for (int fo = 0; fo < 32; ++fo) hw[fo * KB] = acc[fo];
}

// -------- main fused kernel: 256 blocks x 512 threads, 4 batch rows/block --------
__global__ __launch_bounds__(512, 1) void gcnn_main(
    const float* __restrict__ x_in, const float* __restrict__ b_symm,
    const float* __restrict__ b_eq, const float2* __restrict__ Ws_hat,
    const float2* __restrict__ Weq_hat, float* __restrict__ out) {
  __shared__ float2 Hs[4 * HS_STRIDE];  // [nb][fi][k], padded slabs
  __shared__ float2 fb[8][256];         // per-wave FFT scratch
  __shared__ float2 twl[256];
  __shared__ float red[8][4];

  const int tid = threadIdx.x;
  const int w = tid >> 6;
  const int lane = tid & 63;

  if (tid < 256) {
    float a = (float)tid * 0.0245436926f;  // 2*pi/256
    twl[tid] = make_float2(cosf(a), -sinf(a));
  }
  if (tid < 32) red[tid >> 2][tid & 3] = 0.f;
  __syncthreads();

  const int b0 = blockIdx.x * 4;

  // Phase 0a: FFT the 4 input rows (waves 0..3)
  if (w < 4) {
    const float* xr = x_in + (size_t)(b0 + w) * NG;
    for (int g = lane; g < NG; g += 64) fb[w][g] = make_float2(xr[g], 0.f);
    wave_fft256(&fb[w][0], twl, lane, false);
  }
  __syncthreads();

  // Phase 0b: H0[nb][f][k] = conj(Xhat)*WsHat (+256*b_symm at k=0)
  {
    const int nb = w & 3;
    const float2* X = &fb[nb][0];
    const int f0 = (w >> 2) * 16;
    for (int f = f0; f < f0 + 16; ++f) {
      const float bs = 256.f * b_symm[f];
      const float2* wsf = Ws_hat + f * KB;
      float2* hrow = Hs + nb * HS_STRIDE + f * KB;
      for (int k = lane; k < KB; k += 64) {
        float2 xk = X[k];
        float2 wv = wsf[k];
        float2 r = make_float2(xk.x * wv.x + xk.y * wv.y,   // conj(x)*w
                               xk.x * wv.y - xk.y * wv.x);
        if (k == 0) r.x += bs;
        hrow[k] = r;
      }
    }
  }
  __syncthreads();

  #pragma unroll 1
  for (int l = 0; l < NLAYER; ++l) {
    // GEMM phase: each lane owns one (nb, k) column -> barrier-free in-place update
    {
      const int nb = lane & 3;
      const int kk = (w << 4) + (lane >> 2);  // 0..127
      gemm_col(Hs, Weq_hat, b_eq, l, nb, kk);
      if (w == 0 && lane < 4) gemm_col(Hs, Weq_hat, b_eq, l, lane, 128);
    }
    __syncthreads();

    // IFFT -> swish -> (FFT | reduce) per (nb, fo) row; rows are task-private
    const bool last = (l == NLAYER - 1);
    for (int t = w; t < 128; t += 8) {
      const int nb = t >> 5;
      const int fo = t & 31;
      float2* S = &fb[w][0];
      float2* hrow = Hs + nb * HS_STRIDE + fo * KB;
      for (int k = lane; k < KB; k += 64) {
        float2 c = hrow[k];
        S[k] = c;
        if (k >= 1 && k < 128) S[256 - k] = make_float2(c.x, -c.y);  // Hermitian fill
      }
      wave_fft256(S, twl, lane, true);  // unnormalized inverse (1/256 folded into weights)
      if (!last) {
        for (int g = lane; g < NG; g += 64) {
          float y = S[g].x;
          float z = y / (1.f + __expf(-y));
          S[g] = make_float2(z, 0.f);
        }
        wave_fft256(S, twl, lane, false);
        for (int k = lane; k < KB; k += 64) hrow[k] = S[k];
      } else {
        float ls = 0.f;
        for (int g = lane; g < NG; g += 64) {
          float y = S[g].x;
          ls += y / (1.f + __expf(-y));
        }
        ls += __shfl_xor(ls, 32);
        ls += __shfl_xor(ls, 16);
        ls += __shfl_xor(ls, 8);
        ls += __shfl_xor(ls, 4);
        ls += __shfl_xor(ls, 2);
        ls += __shfl_xor(ls, 1);
        if (lane == 0) red[w][nb] += ls;
      }
    }
    __syncthreads();
  }

  if (tid < 4) {
    float s = 0.f;
    #pragma unroll
    for (int ww = 0; ww < 8; ++ww) s += red[ww][tid];
    out[b0 + tid] = s * (1.f / 8192.f);
  }
}

extern "C" void kernel_launch(void* const* d_in, const int* in_sizes, int n_in,
                              void* d_out, int out_size, void* d_ws, size_t ws_size,
                              hipStream_t stream) {
  const float* x_in   = (const float*)d_in[0];
  // d_in[1] = perms, d_in[2] = group_algebra: structure is hard-coded (cyclic group)
  const float* w_symm = (const float*)d_in[3];
  const float* b_symm = (const float*)d_in[4];
  const float* w_eq   = (const float*)d_in[5];
  const float* b_eq   = (const float*)d_in[6];
  float* out = (float*)d_out;

  float2* Ws_hat  = (float2*)d_ws;            // 32*129 complex
  float2* Weq_hat = Ws_hat + 32 * KB;         // 3*32*32*129 complex (~3.2 MB total)

  hipLaunchKernelGGL(gcnn_wfft, dim3(776), dim3(256), 0, stream,
                     w_symm, w_eq, Ws_hat, Weq_hat);
  hipLaunchKernelGGL(gcnn_main, dim3(256), dim3(512), 0, stream,
                     x_in, b_symm, b_eq, Ws_hat, Weq_hat, out);
}

// Round 3
// 223.690 us; speedup vs baseline: 1.8557x; 1.8557x over previous
//
#include <hip/hip_runtime.h>

// GCNN via FFT over the cyclic group C_256.
//
// DenseSymm:  x0[b,f,g] = sum_i x[b,i] w_symm[(i+g)%N, f] + b_symm[f]
//             -> Fourier: H0[b,f,k] = conj(Xhat[b,k]) * WsHat[k,f]  (+ 256*b_symm at k=0)
// Eq layer l: y[b,fo,go] = sum_{gi,fi} x[b,fi,gi] w_eq[l,(go-gi)%G,fi,fo] + b_eq
//             -> Fourier: Yhat[b,fo,k] = sum_fi Hhat[b,fi,k] * WeqHat[l,k,fi,fo]
//             (WeqHat pre-scaled by 1/256 so the inverse FFT is unnormalized;
//              bias is added at bin k=0 which adds it to every g)
// Real signals -> Hermitian spectra: only bins 0..128 stored.
// Pair-packing: rows (2p, 2p+1) share one complex FFT (Z = A + iB).
// All FFT-buffer accesses go through an XOR bank swizzle (<=4 lanes/bank-pair,
// the wave64 ds_*_b64 minimum) to kill the 8/16-way conflicts of pow2 strides.

#define NG 256
#define NF 32
#define KB 129
#define NLAYER 3
#define HS_STRIDE 4132  // 32*129 + 4 pad (float2 units) per nb-slab

__device__ __forceinline__ int swz(int a) {
  int h = a >> 4;
  return a ^ ((h ^ (h << 1)) & 15);
}

// -------- one-wave in-LDS radix-2 FFT of 256 complex points (swizzled) --------
__device__ __forceinline__ void wave_fft256(float2* __restrict__ s,
                                            const float2* __restrict__ tw,
                                            int lane, bool inv) {
  asm volatile("s_waitcnt lgkmcnt(0)" ::: "memory");
  // bit-reversal permutation (8-bit)
  #pragma unroll
  for (int t = 0; t < 4; ++t) {
    int i = t * 64 + lane;
    int j = (int)(__brev((unsigned)i) >> 24);
    if (j > i) {
      float2 a = s[swz(i)]; float2 b = s[swz(j)];
      s[swz(i)] = b; s[swz(j)] = a;
    }
  }
  asm volatile("s_waitcnt lgkmcnt(0)" ::: "memory");
  #pragma unroll
  for (int st = 0; st < 8; ++st) {
    const int half = 1 << st;
    const int tshift = 7 - st;
    #pragma unroll
    for (int t = 0; t < 2; ++t) {
      int bf = t * 64 + lane;              // butterfly id 0..127
      int off = bf & (half - 1);
      int blk = bf >> st;
      int i = (blk << (st + 1)) + off;
      int j = i + half;
      float2 wv = tw[swz(off << tshift)];
      float wy = inv ? -wv.y : wv.y;
      float2 u = s[swz(i)];
      float2 v = s[swz(j)];
      float vr = v.x * wv.x - v.y * wy;
      float vi = v.x * wy + v.y * wv.x;
      s[swz(i)] = make_float2(u.x + vr, u.y + vi);
      s[swz(j)] = make_float2(u.x - vr, u.y - vi);
    }
    asm volatile("s_waitcnt lgkmcnt(0)" ::: "memory");
  }
}

// -------- weight FFT prep: WsHat[f][k], WeqHat[((l*32+fi)*129+k)*32+fo] --------
__global__ __launch_bounds__(256) void gcnn_wfft(
    const float* __restrict__ w_symm, const float* __restrict__ w_eq,
    float2* __restrict__ Ws_hat, float2* __restrict__ Weq_hat) {
  __shared__ float2 fbw[4][256];
  __shared__ float2 twl[256];
  const int tid = threadIdx.x;
  const int w = tid >> 6;
  const int lane = tid & 63;
  {
    float a = (float)tid * 0.0245436926f;  // 2*pi/256
    twl[swz(tid)] = make_float2(cosf(a), -sinf(a));
  }
  __syncthreads();
  const int task = blockIdx.x * 4 + w;  // grid 776 * 4 = 3104 tasks exactly
  if (task < 32) {
    const int f = task;
    for (int g = lane; g < 256; g += 64)
      fbw[w][swz(g)] = make_float2(w_symm[g * 32 + f], 0.f);
    wave_fft256(&fbw[w][0], twl, lane, false);
    for (int k = lane; k < KB; k += 64) Ws_hat[f * KB + k] = fbw[w][swz(k)];
  } else {
    const int idx = task - 32;
    const int l = idx >> 10;
    const int fi = (idx >> 5) & 31;
    const int fo = idx & 31;
    for (int g = lane; g < 256; g += 64)
      fbw[w][swz(g)] = make_float2(w_eq[((size_t)(l * 256 + g) * 32 + fi) * 32 + fo] * (1.f / 256.f), 0.f);
    wave_fft256(&fbw[w][0], twl, lane, false);
    for (int k = lane; k < KB; k += 64)
      Weq_hat[((size_t)((l * 32 + fi) * KB + k)) * 32 + fo] = fbw[w][swz(k)];
  }
}

// -------- per-lane spectral GEMM on one (nb, k) column, in place --------
__device__ __forceinline__ void gemm_col(float2* __restrict__ Hs,
                                         const float2* __restrict__ Weq_hat,
                                         const float* __restrict__ b_eq,
                                         int l, int nb, int k) {
  float2 acc[32];
  #pragma unroll
  for (int fo = 0; fo < 32; ++fo) acc[fo] = make_float2(0.f, 0.f);
  const float2* hcol = Hs + nb * HS_STRIDE + k;
  #pragma unroll 2
  for (int fi = 0; fi < 32; ++fi) {
    float2 h = hcol[fi * KB];
    const float4* wp = reinterpret_cast<const float4*>(
        Weq_hat + ((size_t)((l * 32 + fi) * KB + k)) * 32);
    #pragma unroll
    for (int q = 0; q < 16; ++q) {
      float4 v = wp[q];
      acc[2 * q].x     += h.x * v.x - h.y * v.y;
      acc[2 * q].y     += h.x * v.y + h.y * v.x;
      acc[2 * q + 1].x += h.x * v.z - h.y * v.w;
      acc[2 * q + 1].y += h.x * v.w + h.y * v.z;
    }
  }
  if (k == 0) {
    #pragma unroll
    for (int fo = 0; fo < 32; ++fo) acc[fo].x += b_eq[l * 32 + fo];
  }
  float2* hw = Hs + nb * HS_STRIDE + k;
  #pragma unroll
  for (int fo = 0; fo < 32; ++fo) hw[fo * KB] = acc[fo];
}

// -------- main fused kernel: 256 blocks x 512 threads, 4 batch rows/block --------
__global__ __launch_bounds__(512, 1) void gcnn_main(
    const float* __restrict__ x_in, const float* __restrict__ b_symm,
    const float* __restrict__ b_eq, const float2* __restrict__ Ws_hat,
    const float2* __restrict__ Weq_hat, float* __restrict__ out) {
  __shared__ float2 Hs[4 * HS_STRIDE];  // [nb][fi][k], padded slabs
  __shared__ float2 fb[8][256];         // per-wave FFT scratch (swizzled)
  __shared__ float2 twl[256];
  __shared__ float red[8][4];

  const int tid = threadIdx.x;
  const int w = tid >> 6;
  const int lane = tid & 63;

  if (tid < 256) {
    float a = (float)tid * 0.0245436926f;  // 2*pi/256
    twl[swz(tid)] = make_float2(cosf(a), -sinf(a));
  }
  if (tid < 32) red[tid >> 2][tid & 3] = 0.f;
  __syncthreads();

  const int b0 = blockIdx.x * 4;

  // Phase 0a: FFT the 4 input rows (waves 0..3)
  if (w < 4) {
    const float* xr = x_in + (size_t)(b0 + w) * NG;
    for (int g = lane; g < NG; g += 64) fb[w][swz(g)] = make_float2(xr[g], 0.f);
    wave_fft256(&fb[w][0], twl, lane, false);
  }
  __syncthreads();

  // Phase 0b: H0[nb][f][k] = conj(Xhat)*WsHat (+256*b_symm at k=0)
  {
    const int nb = w & 3;
    const float2* X = &fb[nb][0];
    const int f0 = (w >> 2) * 16;
    for (int f = f0; f < f0 + 16; ++f) {
      const float bs = 256.f * b_symm[f];
      const float2* wsf = Ws_hat + f * KB;
      float2* hrow = Hs + nb * HS_STRIDE + f * KB;
      for (int k = lane; k < KB; k += 64) {
        float2 xk = X[swz(k)];
        float2 wv = wsf[k];
        float2 r = make_float2(xk.x * wv.x + xk.y * wv.y,   // conj(x)*w
                               xk.x * wv.y - xk.y * wv.x);
        if (k == 0) r.x += bs;
        hrow[k] = r;
      }
    }
  }
  __syncthreads();

  #pragma unroll 1
  for (int l = 0; l < NLAYER; ++l) {
    // GEMM phase: each lane owns one (nb, k<=127) column; in-place update.
    {
      const int nb = lane & 3;
      const int kk = (w << 4) + (lane >> 2);  // 0..127
      gemm_col(Hs, Weq_hat, b_eq, l, nb, kk);
    }
    // k=128 column, fo-split across waves 0-1 (each task: 32-fi dot, 128 FMA)
    if (tid < 128) {
      const int nb = tid >> 5;
      const int fo = tid & 31;
      const float2* hcol = Hs + nb * HS_STRIDE + 128;
      float2 acc = make_float2(0.f, 0.f);
      #pragma unroll 4
      for (int fi = 0; fi < 32; ++fi) {
        float2 h = hcol[fi * KB];
        float2 v = Weq_hat[((size_t)((l * 32 + fi) * KB + 128)) * 32 + fo];
        acc.x += h.x * v.x - h.y * v.y;
        acc.y += h.x * v.y + h.y * v.x;
      }
      (Hs + nb * HS_STRIDE + 128)[fo * KB] = acc;  // lockstep: all reads precede writes
    }
    __syncthreads();

    // Pair-packed IFFT -> swish -> (FFT | reduce). Task = (nb, p): rows 2p,2p+1.
    const bool last = (l == NLAYER - 1);
    for (int t = w; t < 64; t += 8) {
      const int nb = t >> 4;
      const int p = t & 15;
      float2* S = &fb[w][0];
      float2* rA = Hs + nb * HS_STRIDE + (2 * p) * KB;
      float2* rB = rA + KB;
      // Build Z = A + iB over all 256 bins (Hermitian extension of both)
      for (int k = lane; k < 128; k += 64) {
        float2 A = rA[k], B = rB[k];
        S[swz(k)] = make_float2(A.x - B.y, A.y + B.x);          // Z_k
        if (k >= 1) {
          S[swz(256 - k)] = make_float2(A.x + B.y, B.x - A.y);  // conj(A)+i*conj(B)
        } else {
          float2 A1 = rA[128], B1 = rB[128];
          S[swz(128)] = make_float2(A1.x - B1.y, A1.y + B1.x);
        }
      }
      wave_fft256(S, twl, lane, true);  // unnormalized inverse (1/256 in weights)
      if (!last) {
        for (int g = lane; g < NG; g += 64) {
          float2 y = S[swz(g)];
          y.x = y.x / (1.f + __expf(-y.x));
          y.y = y.y / (1.f + __expf(-y.y));
          S[swz(g)] = y;
        }
        wave_fft256(S, twl, lane, false);
        // Extract A,B spectra for bins 0..128
        for (int k = lane; k < KB; k += 64) {
          float2 Zk = S[swz(k)];
          float2 Zm = S[swz((256 - k) & 255)];
          float2 A = make_float2(0.5f * (Zk.x + Zm.x), 0.5f * (Zk.y - Zm.y));
          float2 D = make_float2(0.5f * (Zk.x - Zm.x), 0.5f * (Zk.y + Zm.y));
          rA[k] = A;
          rB[k] = make_float2(D.y, -D.x);  // -i*D
        }
      } else {
        float ls = 0.f;
        for (int g = lane; g < NG; g += 64) {
          float2 y = S[swz(g)];
          ls += y.x / (1.f + __expf(-y.x));
          ls += y.y / (1.f + __expf(-y.y));
        }
        ls += __shfl_xor(ls, 32);
        ls += __shfl_xor(ls, 16);
        ls += __shfl_xor(ls, 8);
        ls += __shfl_xor(ls, 4);
        ls += __shfl_xor(ls, 2);
        ls += __shfl_xor(ls, 1);
        if (lane == 0) red[w][nb] += ls;
      }
    }
    __syncthreads();
  }

  if (tid < 4) {
    float s = 0.f;
    #pragma unroll
    for (int ww = 0; ww < 8; ++ww) s += red[ww][tid];
    out[b0 + tid] = s * (1.f / 8192.f);
  }
}

extern "C" void kernel_launch(void* const* d_in, const int* in_sizes, int n_in,
                              void* d_out, int out_size, void* d_ws, size_t ws_size,
                              hipStream_t stream) {
  const float* x_in   = (const float*)d_in[0];
  // d_in[1] = perms, d_in[2] = group_algebra: structure is hard-coded (cyclic group)
  const float* w_symm = (const float*)d_in[3];
  const float* b_symm = (const float*)d_in[4];
  const float* w_eq   = (const float*)d_in[5];
  const float* b_eq   = (const float*)d_in[6];
  float* out = (float*)d_out;

  float2* Ws_hat  = (float2*)d_ws;            // 32*129 complex
  float2* Weq_hat = Ws_hat + 32 * KB;         // 3*32*32*129 complex (~3.2 MB total)

  hipLaunchKernelGGL(gcnn_wfft, dim3(776), dim3(256), 0, stream,
                     w_symm, w_eq, Ws_hat, Weq_hat);
  hipLaunchKernelGGL(gcnn_main, dim3(256), dim3(512), 0, stream,
                     x_in, b_symm, b_eq, Ws_hat, Weq_hat, out);
}